// Round 1
// baseline (2816.714 us; speedup 1.0000x reference)
//
#include <hip/hip_runtime.h>
#include <hip/hip_bf16.h>
#include <math.h>

#define N_ATOMS 524288
#define DIM 256
#define NB 16384          // number of molecules / segments
#define M_STEPS 6
#define SEG_CAP 2048      // max atoms per segment we buffer (Poisson(32) -> max ~70)

// ---------------------------------------------------------------------------
// Kernel 1: segment bounds via binary search (atom_split is sorted)
// lb[b] = first index i with split[i] >= b, for b in [0, NB]; seg b = [lb[b], lb[b+1])
// ---------------------------------------------------------------------------
__global__ void bounds_kernel(const int* __restrict__ split, int* __restrict__ lb) {
    int b = blockIdx.x * blockDim.x + threadIdx.x;
    if (b > NB) return;
    int lo = 0, hi = N_ATOMS;
    while (lo < hi) {
        int mid = (lo + hi) >> 1;
        if (split[mid] < b) lo = mid + 1; else hi = mid;
    }
    lb[b] = lo;
}

// ---------------------------------------------------------------------------
// Kernel 2: fused segment attention. One block per segment.
// e[n] = dot(x[n], h[b]); a = softmax over segment (UNstabilized, matches ref);
// r[b] = sum_n a[n] * x[n]
// ---------------------------------------------------------------------------
__global__ __launch_bounds__(256) void attn_kernel(
    const float* __restrict__ x,      // [N_ATOMS, DIM]
    const int* __restrict__ lb,       // [NB+1]
    const float* __restrict__ h,      // [NB, DIM]
    float* __restrict__ r)            // [NB, DIM]
{
    __shared__ __align__(16) float h_s[DIM];
    __shared__ float w_s[SEG_CAP];
    __shared__ float partial[4];

    const int b = blockIdx.x;
    const int t = threadIdx.x;
    const int s = lb[b];
    int cnt = lb[b + 1] - s;
    if (cnt > SEG_CAP) cnt = SEG_CAP;   // practically unreachable safety clamp
    const int e = s + cnt;

    h_s[t] = h[(size_t)b * DIM + t];
    __syncthreads();

    const int wave = t >> 6;
    const int lane = t & 63;

    // ---- pass 1: e_exp per atom + segment sum ----
    const float4 hv = *(const float4*)(&h_s[lane * 4]);
    float local_sum = 0.0f;
    for (int i = s + wave; i < e; i += 4) {
        const float4 xv = *(const float4*)(&x[(size_t)i * DIM + lane * 4]);
        float dot = xv.x * hv.x + xv.y * hv.y + xv.z * hv.z + xv.w * hv.w;
        #pragma unroll
        for (int off = 32; off > 0; off >>= 1)
            dot += __shfl_xor(dot, off, 64);
        float ee = expf(dot);            // all lanes identical
        if (lane == 0) w_s[i - s] = ee;
        local_sum += ee;
    }
    if (lane == 0) partial[wave] = local_sum;
    __syncthreads();

    const float total = partial[0] + partial[1] + partial[2] + partial[3];
    const float inv = 1.0f / total;      // cnt==0 -> inf, never used (loop empty)

    // ---- pass 2: r[d] = sum_n a[n] * x[n][d]; thread t owns dim t ----
    float acc = 0.0f;
    for (int i = s; i < e; ++i) {
        const float w = w_s[i - s] * inv;                 // LDS broadcast
        acc += w * x[(size_t)i * DIM + t];                // coalesced re-read (L1/L2 hot)
    }
    r[(size_t)b * DIM + t] = acc;
}

// ---------------------------------------------------------------------------
// Kernel 3: fused LSTM step.  z = [h|r] @ U + bias, gates, c/h update.
// Each block: 64 rows x (4 gates x 64 cols) so epilogue has all 4 gates.
// h is double-buffered (read h_in whole-row, write h_out column slice).
// ---------------------------------------------------------------------------
#define BM 64
#define BK 16
__global__ __launch_bounds__(256) void lstm_kernel(
    const float* __restrict__ h_in,   // [NB, DIM]  (A cols 0..255)
    const float* __restrict__ r,      // [NB, DIM]  (A cols 256..511)
    const float* __restrict__ U,      // [512, 1024]
    const float* __restrict__ bias,   // [1024]
    float* __restrict__ c,            // [NB, DIM] in/out
    float* __restrict__ h_out)        // [NB, DIM]
{
    __shared__ __align__(16) float As[BK][BM];        // [k][m]
    __shared__ __align__(16) float Bs[4][BK][64];     // [gate][k][n]

    const int m0 = blockIdx.y * BM;
    const int n0 = blockIdx.x * 64;
    const int t  = threadIdx.x;
    const int ty = t >> 4;            // 0..15 -> 4 rows each
    const int tx = t & 15;            // 0..15 -> 4 cols each

    float acc[4][4][4];               // [gate][row][col]
    #pragma unroll
    for (int g = 0; g < 4; ++g)
        #pragma unroll
        for (int i = 0; i < 4; ++i)
            #pragma unroll
            for (int j = 0; j < 4; ++j) acc[g][i][j] = 0.0f;

    const int lrow = t >> 2;          // A-tile load: 64 rows x 4 float4
    const int lkq  = (t & 3) * 4;
    const int bk   = t >> 4;          // B-tile load: 16 k x 16 float4
    const int bnq  = (t & 15) * 4;

    for (int k0 = 0; k0 < 512; k0 += BK) {
        const float* A = (k0 < 256) ? h_in : r;
        const int ak = k0 & 255;
        {
            float4 v = *(const float4*)(&A[(size_t)(m0 + lrow) * DIM + ak + lkq]);
            As[lkq + 0][lrow] = v.x;
            As[lkq + 1][lrow] = v.y;
            As[lkq + 2][lrow] = v.z;
            As[lkq + 3][lrow] = v.w;
        }
        #pragma unroll
        for (int g = 0; g < 4; ++g) {
            float4 v = *(const float4*)(&U[(size_t)(k0 + bk) * 1024 + g * 256 + n0 + bnq]);
            *(float4*)(&Bs[g][bk][bnq]) = v;
        }
        __syncthreads();

        #pragma unroll
        for (int k = 0; k < BK; ++k) {
            const float4 a4 = *(const float4*)(&As[k][ty * 4]);
            const float av[4] = {a4.x, a4.y, a4.z, a4.w};
            #pragma unroll
            for (int g = 0; g < 4; ++g) {
                const float4 b4 = *(const float4*)(&Bs[g][k][tx * 4]);
                const float bv[4] = {b4.x, b4.y, b4.z, b4.w};
                #pragma unroll
                for (int i = 0; i < 4; ++i)
                    #pragma unroll
                    for (int j = 0; j < 4; ++j)
                        acc[g][i][j] += av[i] * bv[j];
            }
        }
        __syncthreads();
    }

    // epilogue: gates + state update
    #pragma unroll
    for (int i = 0; i < 4; ++i) {
        const int row = m0 + ty * 4 + i;
        #pragma unroll
        for (int j = 0; j < 4; ++j) {
            const int col = n0 + tx * 4 + j;
            const float zi = acc[0][i][j] + bias[col];
            const float zf = acc[1][i][j] + bias[256 + col];
            const float zo = acc[2][i][j] + bias[512 + col];
            const float zg = acc[3][i][j] + bias[768 + col];
            const float ig = 1.0f / (1.0f + expf(-zi));
            const float fg = 1.0f / (1.0f + expf(-zf));
            const float og = 1.0f / (1.0f + expf(-zo));
            const float gg = tanhf(zg);
            const size_t idx = (size_t)row * DIM + col;
            const float cn = fg * c[idx] + ig * gg;
            c[idx] = cn;
            h_out[idx] = og * tanhf(cn);
        }
    }
}

// ---------------------------------------------------------------------------
// Kernel 4: q_star = concat([h, r], axis=1) -> d_out [NB, 2*DIM]
// one float4 per thread
// ---------------------------------------------------------------------------
__global__ __launch_bounds__(256) void writeout_kernel(
    const float* __restrict__ h, const float* __restrict__ r,
    float* __restrict__ out)
{
    const int idx = blockIdx.x * 256 + threadIdx.x;   // NB*128 float4s total
    const int b  = idx >> 7;
    const int j4 = idx & 127;
    const float* src = (j4 < 64) ? &h[(size_t)b * DIM + j4 * 4]
                                 : &r[(size_t)b * DIM + (j4 - 64) * 4];
    *(float4*)(&out[(size_t)b * 512 + j4 * 4]) = *(const float4*)src;
}

// ---------------------------------------------------------------------------
extern "C" void kernel_launch(void* const* d_in, const int* in_sizes, int n_in,
                              void* d_out, int out_size, void* d_ws, size_t ws_size,
                              hipStream_t stream) {
    const float* x     = (const float*)d_in[0];   // [N_ATOMS, DIM]
    const int*   split = (const int*)d_in[1];     // [N_ATOMS]
    const float* U     = (const float*)d_in[2];   // [512, 1024]
    const float* bias  = (const float*)d_in[3];   // [1024]
    float* out = (float*)d_out;

    // workspace layout (16B-aligned blocks)
    char* ws = (char*)d_ws;
    const size_t lb_bytes  = ((size_t)(NB + 1) * sizeof(int) + 255) & ~(size_t)255;
    const size_t mat_bytes = (size_t)NB * DIM * sizeof(float);   // 16 MB
    int*   lb = (int*)ws;
    float* h0 = (float*)(ws + lb_bytes);
    float* h1 = (float*)(ws + lb_bytes + mat_bytes);
    float* cbuf = (float*)(ws + lb_bytes + 2 * mat_bytes);
    float* rbuf = (float*)(ws + lb_bytes + 3 * mat_bytes);

    bounds_kernel<<<(NB + 1 + 255) / 256, 256, 0, stream>>>(split, lb);
    hipMemsetAsync(h0, 0, mat_bytes, stream);
    hipMemsetAsync(cbuf, 0, mat_bytes, stream);

    float* h_cur = h0;
    float* h_nxt = h1;
    for (int m = 0; m < M_STEPS; ++m) {
        attn_kernel<<<NB, 256, 0, stream>>>(x, lb, h_cur, rbuf);
        if (m < M_STEPS - 1) {
            dim3 grid(4, NB / BM);   // 4 n-tiles x 256 m-tiles
            lstm_kernel<<<grid, 256, 0, stream>>>(h_cur, rbuf, U, bias, cbuf, h_nxt);
            float* tmp = h_cur; h_cur = h_nxt; h_nxt = tmp;
        }
    }
    writeout_kernel<<<(NB * 128) / 256, 256, 0, stream>>>(h_cur, rbuf, out);
}

// Round 2
// 2049.611 us; speedup vs baseline: 1.3743x; 1.3743x over previous
//
#include <hip/hip_runtime.h>
#include <hip/hip_bf16.h>
#include <math.h>

#define N_ATOMS 524288
#define DIM 256
#define NB 16384          // number of molecules / segments
#define M_STEPS 6
#define SEG_CAP 2048      // max atoms per segment we buffer (Poisson(32) -> max ~70)

typedef short bf16x8 __attribute__((ext_vector_type(8)));
typedef float f32x16 __attribute__((ext_vector_type(16)));

__device__ __forceinline__ unsigned short f2bf(float f) {
    union { float f; unsigned u; } x; x.f = f;
    unsigned r = x.u + 0x7FFFu + ((x.u >> 16) & 1u);   // round-nearest-even
    return (unsigned short)(r >> 16);
}
__device__ __forceinline__ float sigmoidf(float z) {
    return 1.0f / (1.0f + __expf(-z));
}

// ---------------------------------------------------------------------------
// Kernel 1: segment bounds via binary search (atom_split is sorted)
// ---------------------------------------------------------------------------
__global__ void bounds_kernel(const int* __restrict__ split, int* __restrict__ lb) {
    int b = blockIdx.x * blockDim.x + threadIdx.x;
    if (b > NB) return;
    int lo = 0, hi = N_ATOMS;
    while (lo < hi) {
        int mid = (lo + hi) >> 1;
        if (split[mid] < b) lo = mid + 1; else hi = mid;
    }
    lb[b] = lo;
}

// ---------------------------------------------------------------------------
// Kernel 2: pre-swizzle U (f32 [512,1024]) into bf16 B-fragment order for
// mfma_f32_32x32x16_bf16. Frag f = nt*32 + kc (nt: 32-col tile, kc: 16-k chunk)
// lane l of frag holds B[k = kc*16 + (l>>5)*8 + jj][n = nt*32 + (l&31)], jj=0..7
// stored as 8 consecutive bf16 at ubf + (f*64 + l)*8.  Total 1 MB.
// ---------------------------------------------------------------------------
__global__ __launch_bounds__(256) void uswz_kernel(const float* __restrict__ U,
                                                   unsigned short* __restrict__ ubf) {
    int d = blockIdx.x * 256 + threadIdx.x;    // [0, 1024 frags * 256)
    int f = d >> 8;
    int r = d & 255;
    int jjp = r >> 6;          // 0..3 (pair of jj)
    int lane = r & 63;
    int nt = f >> 5, kc = f & 31;
    int n = nt * 32 + (lane & 31);
    int k = kc * 16 + (lane >> 5) * 8 + jjp * 2;
    unsigned short b0 = f2bf(U[(size_t)k * 1024 + n]);
    unsigned short b1 = f2bf(U[(size_t)(k + 1) * 1024 + n]);
    ushort2 p; p.x = b0; p.y = b1;
    *(ushort2*)(&ubf[(size_t)(f * 64 + lane) * 8 + jjp * 2]) = p;
}

// ---------------------------------------------------------------------------
// Kernel 3: fused segment attention. One block per segment.
// ---------------------------------------------------------------------------
__global__ __launch_bounds__(256) void attn_kernel(
    const float* __restrict__ x,      // [N_ATOMS, DIM]
    const int* __restrict__ lb,       // [NB+1]
    const float* __restrict__ h,      // [NB, DIM]
    float* __restrict__ r)            // [NB, DIM]
{
    __shared__ __align__(16) float h_s[DIM];
    __shared__ float w_s[SEG_CAP];
    __shared__ float partial[4];

    const int b = blockIdx.x;
    const int t = threadIdx.x;
    const int s = lb[b];
    int cnt = lb[b + 1] - s;
    if (cnt > SEG_CAP) cnt = SEG_CAP;
    const int e = s + cnt;

    h_s[t] = h[(size_t)b * DIM + t];
    __syncthreads();

    const int wave = t >> 6;
    const int lane = t & 63;

    const float4 hv = *(const float4*)(&h_s[lane * 4]);
    float local_sum = 0.0f;
    for (int i = s + wave; i < e; i += 4) {
        const float4 xv = *(const float4*)(&x[(size_t)i * DIM + lane * 4]);
        float dot = xv.x * hv.x + xv.y * hv.y + xv.z * hv.z + xv.w * hv.w;
        #pragma unroll
        for (int off = 32; off > 0; off >>= 1)
            dot += __shfl_xor(dot, off, 64);
        float ee = expf(dot);
        if (lane == 0) w_s[i - s] = ee;
        local_sum += ee;
    }
    if (lane == 0) partial[wave] = local_sum;
    __syncthreads();

    const float total = partial[0] + partial[1] + partial[2] + partial[3];
    const float inv = 1.0f / total;

    float acc = 0.0f;
    for (int i = s; i < e; ++i) {
        const float w = w_s[i - s] * inv;
        acc += w * x[(size_t)i * DIM + t];
    }
    r[(size_t)b * DIM + t] = acc;
}

// ---------------------------------------------------------------------------
// Kernel 4: fused LSTM step via bf16 MFMA.
// Block: 128 rows x 256 effective cols (4 gates x 64 cols at n0 = bx*64).
// 4 waves, wave w: rows [m0+w*32, +32), 8 MFMA tiles (32x32) across eff cols.
// A = [h | r] staged f32->bf16 via LDS; B-frags direct from pre-swizzled ubf.
// Epilogue: all 4 gates in-lane -> c/h update, no z materialization.
// ---------------------------------------------------------------------------
#define LBM 128
#define LBK 64
#define APAD 8   // pad A rows to 72 bf16 so frag reads spread banks
__global__ __launch_bounds__(256, 2) void lstm_mfma_kernel(
    const float* __restrict__ h_in,   // [NB, DIM]
    const float* __restrict__ r,      // [NB, DIM]
    const unsigned short* __restrict__ ubf,  // swizzled U, bf16
    const float* __restrict__ bias,   // [1024]
    float* __restrict__ c,            // [NB, DIM] in/out
    float* __restrict__ h_out)        // [NB, DIM]
{
    __shared__ unsigned short As[LBM][LBK + APAD];   // 18 KB

    const int t = threadIdx.x;
    const int w = t >> 6;
    const int lane = t & 63;
    const int m0 = blockIdx.y * LBM;
    const int bx = blockIdx.x;       // n0 = bx*64 within each gate

    f32x16 acc[8];
    #pragma unroll
    for (int et = 0; et < 8; ++et)
        #pragma unroll
        for (int q = 0; q < 16; ++q) acc[et][q] = 0.0f;

    for (int kb = 0; kb < 8; ++kb) {           // K = 512 in chunks of 64
        const float* A = (kb < 4) ? h_in : r;
        const int ak = (kb & 3) * LBK;
        __syncthreads();
        #pragma unroll
        for (int i = 0; i < 8; ++i) {          // stage 128x64 f32 -> bf16 LDS
            int idx = i * 256 + t;
            int row = idx >> 4, k4 = idx & 15;
            float4 v = *(const float4*)(&A[(size_t)(m0 + row) * DIM + ak + k4 * 4]);
            ushort4 bv;
            bv.x = f2bf(v.x); bv.y = f2bf(v.y); bv.z = f2bf(v.z); bv.w = f2bf(v.w);
            *(ushort4*)(&As[row][k4 * 4]) = bv;
        }
        __syncthreads();
        #pragma unroll
        for (int kc = 0; kc < 4; ++kc) {       // 4 k-chunks of 16
            bf16x8 af = *(const bf16x8*)(&As[w * 32 + (lane & 31)][kc * 16 + (lane >> 5) * 8]);
            const int kglob = kb * 4 + kc;     // global k-chunk 0..31
            #pragma unroll
            for (int et = 0; et < 8; ++et) {
                const int g = et >> 1;
                const int nt = g * 8 + bx * 2 + (et & 1);
                bf16x8 bfr = *(const bf16x8*)(&ubf[((size_t)(nt * 32 + kglob) * 64 + lane) * 8]);
                acc[et] = __builtin_amdgcn_mfma_f32_32x32x16_bf16(af, bfr, acc[et], 0, 0, 0);
            }
        }
    }

    // epilogue: C/D layout col=lane&31, row=(reg&3)+8*(reg>>2)+4*(lane>>5)
    const int col32 = lane & 31;
    const int rbase = m0 + w * 32 + 4 * (lane >> 5);
    #pragma unroll
    for (int jh = 0; jh < 2; ++jh) {
        const int col = bx * 64 + jh * 32 + col32;
        const float bi = bias[col];
        const float bf_ = bias[256 + col];
        const float bo = bias[512 + col];
        const float bg = bias[768 + col];
        const f32x16 zi = acc[0 * 2 + jh];
        const f32x16 zf = acc[1 * 2 + jh];
        const f32x16 zo = acc[2 * 2 + jh];
        const f32x16 zg = acc[3 * 2 + jh];
        #pragma unroll
        for (int reg = 0; reg < 16; ++reg) {
            const int row = rbase + (reg & 3) + 8 * (reg >> 2);
            const size_t idx = (size_t)row * DIM + col;
            const float ig = sigmoidf(zi[reg] + bi);
            const float fg = sigmoidf(zf[reg] + bf_);
            const float og = sigmoidf(zo[reg] + bo);
            const float gg = tanhf(zg[reg] + bg);
            const float cn = fg * c[idx] + ig * gg;
            c[idx] = cn;
            h_out[idx] = og * tanhf(cn);
        }
    }
}

// ---------------------------------------------------------------------------
// Kernel 5: q_star = concat([h, r], axis=1) -> d_out [NB, 2*DIM]
// ---------------------------------------------------------------------------
__global__ __launch_bounds__(256) void writeout_kernel(
    const float* __restrict__ h, const float* __restrict__ r,
    float* __restrict__ out)
{
    const int idx = blockIdx.x * 256 + threadIdx.x;
    const int b  = idx >> 7;
    const int j4 = idx & 127;
    const float* src = (j4 < 64) ? &h[(size_t)b * DIM + j4 * 4]
                                 : &r[(size_t)b * DIM + (j4 - 64) * 4];
    *(float4*)(&out[(size_t)b * 512 + j4 * 4]) = *(const float4*)src;
}

// ---------------------------------------------------------------------------
extern "C" void kernel_launch(void* const* d_in, const int* in_sizes, int n_in,
                              void* d_out, int out_size, void* d_ws, size_t ws_size,
                              hipStream_t stream) {
    const float* x     = (const float*)d_in[0];   // [N_ATOMS, DIM]
    const int*   split = (const int*)d_in[1];     // [N_ATOMS]
    const float* U     = (const float*)d_in[2];   // [512, 1024]
    const float* bias  = (const float*)d_in[3];   // [1024]
    float* out = (float*)d_out;

    char* ws = (char*)d_ws;
    const size_t lb_bytes  = ((size_t)(NB + 1) * sizeof(int) + 255) & ~(size_t)255;
    const size_t mat_bytes = (size_t)NB * DIM * sizeof(float);   // 16 MB
    int*   lb   = (int*)ws;
    float* h0   = (float*)(ws + lb_bytes);
    float* h1   = (float*)(ws + lb_bytes + mat_bytes);
    float* cbuf = (float*)(ws + lb_bytes + 2 * mat_bytes);
    float* rbuf = (float*)(ws + lb_bytes + 3 * mat_bytes);
    unsigned short* ubf = (unsigned short*)(ws + lb_bytes + 4 * mat_bytes); // 1 MB

    bounds_kernel<<<(NB + 1 + 255) / 256, 256, 0, stream>>>(split, lb);
    uswz_kernel<<<1024, 256, 0, stream>>>(U, ubf);
    hipMemsetAsync(h0, 0, mat_bytes, stream);
    hipMemsetAsync(cbuf, 0, mat_bytes, stream);

    float* h_cur = h0;
    float* h_nxt = h1;
    for (int m = 0; m < M_STEPS; ++m) {
        attn_kernel<<<NB, 256, 0, stream>>>(x, lb, h_cur, rbuf);
        if (m < M_STEPS - 1) {
            dim3 grid(4, NB / LBM);   // 4 col-blocks x 128 row-blocks
            lstm_mfma_kernel<<<grid, 256, 0, stream>>>(h_cur, rbuf, ubf, bias, cbuf, h_nxt);
            float* tmp = h_cur; h_cur = h_nxt; h_nxt = tmp;
        }
    }
    writeout_kernel<<<(NB * 128) / 256, 256, 0, stream>>>(h_cur, rbuf, out);
}

// Round 3
// 1559.274 us; speedup vs baseline: 1.8064x; 1.3145x over previous
//
#include <hip/hip_runtime.h>
#include <hip/hip_bf16.h>
#include <math.h>

#define N_ATOMS 524288
#define DIM 256
#define NB 16384          // number of molecules / segments
#define M_STEPS 6

typedef short bf16x8 __attribute__((ext_vector_type(8)));
typedef float f32x16 __attribute__((ext_vector_type(16)));

__device__ __forceinline__ unsigned short f2bf(float f) {
    union { float f; unsigned u; } x; x.f = f;
    unsigned r = x.u + 0x7FFFu + ((x.u >> 16) & 1u);   // round-nearest-even
    return (unsigned short)(r >> 16);
}
__device__ __forceinline__ float sigmoidf(float z) {
    return 1.0f / (1.0f + __expf(-z));
}

// ---------------------------------------------------------------------------
// Kernel 1: segment bounds via binary search (atom_split is sorted)
// ---------------------------------------------------------------------------
__global__ void bounds_kernel(const int* __restrict__ split, int* __restrict__ lb) {
    int b = blockIdx.x * blockDim.x + threadIdx.x;
    if (b > NB) return;
    int lo = 0, hi = N_ATOMS;
    while (lo < hi) {
        int mid = (lo + hi) >> 1;
        if (split[mid] < b) lo = mid + 1; else hi = mid;
    }
    lb[b] = lo;
}

// ---------------------------------------------------------------------------
// Kernel 2: pre-swizzle U (f32 [512,1024]) into bf16 B-fragment order for
// mfma_f32_32x32x16_bf16. Frag f = nt*32 + kc; lane l holds
// B[k = kc*16 + (l>>5)*8 + jj][n = nt*32 + (l&31)], jj=0..7. 1 MB total.
// ---------------------------------------------------------------------------
__global__ __launch_bounds__(256) void uswz_kernel(const float* __restrict__ U,
                                                   unsigned short* __restrict__ ubf) {
    int d = blockIdx.x * 256 + threadIdx.x;
    int f = d >> 8;
    int r = d & 255;
    int jjp = r >> 6;
    int lane = r & 63;
    int nt = f >> 5, kc = f & 31;
    int n = nt * 32 + (lane & 31);
    int k = kc * 16 + (lane >> 5) * 8 + jjp * 2;
    unsigned short b0 = f2bf(U[(size_t)k * 1024 + n]);
    unsigned short b1 = f2bf(U[(size_t)(k + 1) * 1024 + n]);
    ushort2 p; p.x = b0; p.y = b1;
    *(ushort2*)(&ubf[(size_t)(f * 64 + lane) * 8 + jjp * 2]) = p;
}

// ---------------------------------------------------------------------------
// Kernel 3: SINGLE-PASS fused segment attention. One block per segment.
// r[b] = (sum_n exp(e_n) x_n) / (sum_n exp(e_n)) — normalizer is a scalar,
// so accumulate unnormalized weighted sum while x_n is in registers.
// One read of x total (512 MB/step instead of ~1 GB).
// ---------------------------------------------------------------------------
__global__ __launch_bounds__(256) void attn_kernel(
    const float* __restrict__ x,      // [N_ATOMS, DIM]
    const int* __restrict__ lb,       // [NB+1]
    const float* __restrict__ h,      // [NB, DIM]
    float* __restrict__ rout,         // output base
    int rstride)                      // row stride of rout
{
    __shared__ __align__(16) float h_s[DIM];
    __shared__ __align__(16) float pr[4][DIM];   // per-wave weighted sums
    __shared__ float psum[4];

    const int b = blockIdx.x;
    const int t = threadIdx.x;
    const int s = lb[b];
    const int e = lb[b + 1];

    h_s[t] = h[(size_t)b * DIM + t];
    __syncthreads();

    const int wave = t >> 6;
    const int lane = t & 63;

    const float4 hv = *(const float4*)(&h_s[lane * 4]);
    float4 racc = {0.f, 0.f, 0.f, 0.f};
    float local_sum = 0.0f;
    for (int i = s + wave; i < e; i += 4) {
        const float4 xv = *(const float4*)(&x[(size_t)i * DIM + lane * 4]);
        float dot = xv.x * hv.x + xv.y * hv.y + xv.z * hv.z + xv.w * hv.w;
        #pragma unroll
        for (int off = 32; off > 0; off >>= 1)
            dot += __shfl_xor(dot, off, 64);
        const float ee = expf(dot);          // broadcast-identical across lanes
        local_sum += ee;
        racc.x += ee * xv.x;
        racc.y += ee * xv.y;
        racc.z += ee * xv.z;
        racc.w += ee * xv.w;
    }
    *(float4*)(&pr[wave][lane * 4]) = racc;
    if (lane == 0) psum[wave] = local_sum;
    __syncthreads();

    const float total = psum[0] + psum[1] + psum[2] + psum[3];
    const float inv = (total > 0.0f) ? 1.0f / total : 0.0f;   // empty segment -> 0
    const float v = (pr[0][t] + pr[1][t] + pr[2][t] + pr[3][t]) * inv;
    rout[(size_t)b * rstride + t] = v;
}

// ---------------------------------------------------------------------------
// Kernel 4: fused LSTM step via bf16 MFMA (unchanged from round 2).
// ---------------------------------------------------------------------------
#define LBM 128
#define LBK 64
#define APAD 8
__global__ __launch_bounds__(256, 2) void lstm_mfma_kernel(
    const float* __restrict__ h_in,
    const float* __restrict__ r,
    const unsigned short* __restrict__ ubf,
    const float* __restrict__ bias,
    float* __restrict__ c,
    float* __restrict__ h_out)
{
    __shared__ unsigned short As[LBM][LBK + APAD];

    const int t = threadIdx.x;
    const int w = t >> 6;
    const int lane = t & 63;
    const int m0 = blockIdx.y * LBM;
    const int bx = blockIdx.x;

    f32x16 acc[8];
    #pragma unroll
    for (int et = 0; et < 8; ++et)
        #pragma unroll
        for (int q = 0; q < 16; ++q) acc[et][q] = 0.0f;

    for (int kb = 0; kb < 8; ++kb) {
        const float* A = (kb < 4) ? h_in : r;
        const int ak = (kb & 3) * LBK;
        __syncthreads();
        #pragma unroll
        for (int i = 0; i < 8; ++i) {
            int idx = i * 256 + t;
            int row = idx >> 4, k4 = idx & 15;
            float4 v = *(const float4*)(&A[(size_t)(m0 + row) * DIM + ak + k4 * 4]);
            ushort4 bv;
            bv.x = f2bf(v.x); bv.y = f2bf(v.y); bv.z = f2bf(v.z); bv.w = f2bf(v.w);
            *(ushort4*)(&As[row][k4 * 4]) = bv;
        }
        __syncthreads();
        #pragma unroll
        for (int kc = 0; kc < 4; ++kc) {
            bf16x8 af = *(const bf16x8*)(&As[w * 32 + (lane & 31)][kc * 16 + (lane >> 5) * 8]);
            const int kglob = kb * 4 + kc;
            #pragma unroll
            for (int et = 0; et < 8; ++et) {
                const int g = et >> 1;
                const int nt = g * 8 + bx * 2 + (et & 1);
                bf16x8 bfr = *(const bf16x8*)(&ubf[((size_t)(nt * 32 + kglob) * 64 + lane) * 8]);
                acc[et] = __builtin_amdgcn_mfma_f32_32x32x16_bf16(af, bfr, acc[et], 0, 0, 0);
            }
        }
    }

    const int col32 = lane & 31;
    const int rbase = m0 + w * 32 + 4 * (lane >> 5);
    #pragma unroll
    for (int jh = 0; jh < 2; ++jh) {
        const int col = bx * 64 + jh * 32 + col32;
        const float bi = bias[col];
        const float bf_ = bias[256 + col];
        const float bo = bias[512 + col];
        const float bg = bias[768 + col];
        const f32x16 zi = acc[0 * 2 + jh];
        const f32x16 zf = acc[1 * 2 + jh];
        const f32x16 zo = acc[2 * 2 + jh];
        const f32x16 zg = acc[3 * 2 + jh];
        #pragma unroll
        for (int reg = 0; reg < 16; ++reg) {
            const int row = rbase + (reg & 3) + 8 * (reg >> 2);
            const size_t idx = (size_t)row * DIM + col;
            const float ig = sigmoidf(zi[reg] + bi);
            const float fg = sigmoidf(zf[reg] + bf_);
            const float og = sigmoidf(zo[reg] + bo);
            const float gg = tanhf(zg[reg] + bg);
            const float cn = fg * c[idx] + ig * gg;
            c[idx] = cn;
            h_out[idx] = og * tanhf(cn);
        }
    }
}

// ---------------------------------------------------------------------------
// Kernel 5: copy h into out[:, :256] (r half is written by the final attn).
// ---------------------------------------------------------------------------
__global__ __launch_bounds__(256) void writeout_h_kernel(
    const float* __restrict__ h, float* __restrict__ out)
{
    const int idx = blockIdx.x * 256 + threadIdx.x;   // NB*64 float4s
    const int b  = idx >> 6;
    const int j4 = idx & 63;
    *(float4*)(&out[(size_t)b * 512 + j4 * 4]) =
        *(const float4*)(&h[(size_t)b * DIM + j4 * 4]);
}

// ---------------------------------------------------------------------------
extern "C" void kernel_launch(void* const* d_in, const int* in_sizes, int n_in,
                              void* d_out, int out_size, void* d_ws, size_t ws_size,
                              hipStream_t stream) {
    const float* x     = (const float*)d_in[0];
    const int*   split = (const int*)d_in[1];
    const float* U     = (const float*)d_in[2];
    const float* bias  = (const float*)d_in[3];
    float* out = (float*)d_out;

    char* ws = (char*)d_ws;
    const size_t lb_bytes  = ((size_t)(NB + 1) * sizeof(int) + 255) & ~(size_t)255;
    const size_t mat_bytes = (size_t)NB * DIM * sizeof(float);   // 16 MB
    int*   lb   = (int*)ws;
    float* h0   = (float*)(ws + lb_bytes);
    float* h1   = (float*)(ws + lb_bytes + mat_bytes);
    float* cbuf = (float*)(ws + lb_bytes + 2 * mat_bytes);
    float* rbuf = (float*)(ws + lb_bytes + 3 * mat_bytes);
    unsigned short* ubf = (unsigned short*)(ws + lb_bytes + 4 * mat_bytes); // 1 MB

    bounds_kernel<<<(NB + 1 + 255) / 256, 256, 0, stream>>>(split, lb);
    uswz_kernel<<<1024, 256, 0, stream>>>(U, ubf);
    hipMemsetAsync(h0, 0, mat_bytes, stream);
    hipMemsetAsync(cbuf, 0, mat_bytes, stream);

    float* h_cur = h0;
    float* h_nxt = h1;
    for (int m = 0; m < M_STEPS; ++m) {
        const bool last = (m == M_STEPS - 1);
        float* rdst   = last ? (out + DIM) : rbuf;
        int    rstrid = last ? (2 * DIM) : DIM;
        attn_kernel<<<NB, 256, 0, stream>>>(x, lb, h_cur, rdst, rstrid);
        if (!last) {
            dim3 grid(4, NB / LBM);
            lstm_mfma_kernel<<<grid, 256, 0, stream>>>(h_cur, rbuf, ubf, bias, cbuf, h_nxt);
            float* tmp = h_cur; h_cur = h_nxt; h_nxt = tmp;
        }
    }
    writeout_h_kernel<<<(NB * 64) / 256, 256, 0, stream>>>(h_cur, out);
}